// Round 6
// baseline (430.263 us; speedup 1.0000x reference)
//
#include <hip/hip_runtime.h>

// SpikeLoss: loss = 0.5 * sum((outputs - psp(target))^2)
// psp: syn_t = syn_{t-1}*0.8 + x_t, emit syn_t/5   (tau=5)
// Shape [B=16, C=128, H=16, W=16, T=100], T contiguous. 524288 neurons.
//
// R6: single-wave workgroups. Block = 64 threads = 1 wave = 16 neurons =
// 64 exactly-mapped 25-step segments. __syncthreads is now a WAVE-PRIVATE
// vmcnt drain (no cross-wave rendezvous); 12 blocks/CU (12.8 KB LDS each)
// run phase-decorrelated, keeping the memory pipe continuously fed.
// DMA staging (no VGPR round-trip), carries via 3 independent shuffles,
// x kept in registers between the two scan passes.

#define T_STEPS 100
#define SEG 25
#define NPB 16                            // neurons per block (= wave)
#define BLOCK 64
#define N_NEURONS (16 * 128 * 16 * 16)    // 524288
#define GRID_P (N_NEURONS / NPB)          // 32768
#define FLOATS_PB (NPB * T_STEPS)         // 1600 floats per array per block
#define F4_PB (FLOATS_PB / 4)             // 400 float4

#define GLOBAL_AS __attribute__((address_space(1)))
#define LDS_AS __attribute__((address_space(3)))

__device__ __forceinline__ void async_f4(const float4* g, float4* l) {
  __builtin_amdgcn_global_load_lds((const GLOBAL_AS void*)g, (LDS_AS void*)l,
                                   16, 0, 0);
}

__device__ __forceinline__ float tile_loss(const float* __restrict__ outputs,
                                           const float* __restrict__ target) {
  __shared__ float xbuf[FLOATS_PB];  // 6.4 KB
  __shared__ float obuf[FLOATS_PB];  // 6.4 KB

  const int tid = threadIdx.x;  // 0..63
  const size_t base = (size_t)blockIdx.x * FLOATS_PB;
  const float4* gt = reinterpret_cast<const float4*>(target + base);
  const float4* go = reinterpret_cast<const float4*>(outputs + base);
  float4* lx4 = reinterpret_cast<float4*>(xbuf);
  float4* lo4 = reinterpret_cast<float4*>(obuf);

  // ---- DMA both arrays into LDS: 6 full wave-loads + 16-lane remainder ----
#pragma unroll
  for (int it = 0; it < 6; ++it) async_f4(gt + it * 64 + tid, lx4 + it * 64 + tid);
  if (tid < F4_PB - 384) async_f4(gt + 384 + tid, lx4 + 384 + tid);
#pragma unroll
  for (int it = 0; it < 6; ++it) async_f4(go + it * 64 + tid, lo4 + it * 64 + tid);
  if (tid < F4_PB - 384) async_f4(go + 384 + tid, lo4 + 384 + tid);

  __syncthreads();  // 1-wave block: private vmcnt drain, no cross-wave stall

  // ---- B1: per-lane segment scan; x -> registers ----
  const int n = tid >> 2;  // neuron 0..15
  const int s = tid & 3;   // segment 0..3
  const float* xrow = xbuf + n * T_STEPS + s * SEG;  // banks: 2-way = free
  float x[SEG];
#pragma unroll
  for (int j = 0; j < SEG; ++j) x[j] = xrow[j];
  float E = 0.f;
#pragma unroll
  for (int j = 0; j < SEG; ++j) E = fmaf(E, 0.8f, x[j]);

  // carry = syn at end of previous segments (exact composition, a^25, a^50)
  float c1 = __shfl_up(E, 1);
  float c2 = __shfl_up(E, 2);
  float c3 = __shfl_up(E, 3);
  float carry = 0.f;
  if (s >= 1) carry = c1;
  if (s >= 2) carry = fmaf(3.77789319e-3f, c2, carry);
  if (s >= 3) carry = fmaf(1.42724769e-5f, c3, carry);

  // ---- B2: rescan with carry seed; accumulate loss ----
  const float* orow = obuf + n * T_STEPS + s * SEG;
  float syn = carry;
  float acc = 0.f;
#pragma unroll
  for (int j = 0; j < SEG; ++j) {
    syn = fmaf(syn, 0.8f, x[j]);
    float d = fmaf(-0.2f, syn, orow[j]);
    acc = fmaf(d, d, acc);
  }

  // ---- wave reduction ----
#pragma unroll
  for (int off = 32; off > 0; off >>= 1) acc += __shfl_down(acc, off, 64);
  return acc;  // valid in lane 0
}

__global__ __launch_bounds__(BLOCK, 3) void spike_loss_partial(
    const float* __restrict__ outputs,
    const float* __restrict__ target,
    float* __restrict__ partial) {
  float acc = tile_loss(outputs, target);
  if (threadIdx.x == 0) partial[blockIdx.x] = acc;
}

// Deterministic final reduction over per-block partials; applies the 0.5.
__global__ __launch_bounds__(256) void spike_loss_final(
    const float* __restrict__ partial, float* __restrict__ out, int nparts) {
  float acc = 0.0f;
  for (int i = threadIdx.x; i < nparts; i += 256) acc += partial[i];
#pragma unroll
  for (int off = 32; off > 0; off >>= 1) acc += __shfl_down(acc, off, 64);
  __shared__ float wsum[4];
  const int lane = threadIdx.x & 63;
  const int wid = threadIdx.x >> 6;
  if (lane == 0) wsum[wid] = acc;
  __syncthreads();
  if (threadIdx.x == 0) out[0] = 0.5f * (wsum[0] + wsum[1] + wsum[2] + wsum[3]);
}

// Fallback if d_ws is unusably small: atomic finish into d_out.
__global__ __launch_bounds__(BLOCK, 3) void spike_loss_atomic(
    const float* __restrict__ outputs,
    const float* __restrict__ target,
    float* __restrict__ out) {
  float acc = tile_loss(outputs, target);
  if (threadIdx.x == 0) atomicAdd(out, 0.5f * acc);
}

extern "C" void kernel_launch(void* const* d_in, const int* in_sizes, int n_in,
                              void* d_out, int out_size, void* d_ws, size_t ws_size,
                              hipStream_t stream) {
  const float* outputs = (const float*)d_in[0];
  const float* target = (const float*)d_in[1];
  float* out = (float*)d_out;

  if (ws_size >= GRID_P * sizeof(float)) {
    float* partial = (float*)d_ws;
    spike_loss_partial<<<GRID_P, BLOCK, 0, stream>>>(outputs, target, partial);
    spike_loss_final<<<1, 256, 0, stream>>>(partial, out, GRID_P);
  } else {
    hipMemsetAsync(out, 0, sizeof(float), stream);
    spike_loss_atomic<<<GRID_P, BLOCK, 0, stream>>>(outputs, target, out);
  }
}